// Round 9
// baseline (44.994 us; speedup 1.0000x reference)
//
#include <hip/hip_runtime.h>

// LIF neuron forward scan: x [B,N,T] f32, T=256 contiguous (last axis).
// u = u*TAU + x_t; s = (u >= VTH); u = s ? 0 : u; emit s.
// TAU=0.125 (2^-3) -> u*TAU exact -> recurrence bit-matches numpy ref.
//
// R9 = R8 + nontemporal COALESCED stores (single change, clean A/B).
//  - R6 post-mortem: NT + scattered 16B/thread stores = partial-granule HBM
//    writes = 375us disaster. R8's coop store is 1KB contiguous per wave
//    instruction (full 64B lines), so NT is safe at HBM granularity.
//  - Goal: output (write-once) stops allocating in L2/L3 -> 128MiB input
//    stays fully L3-resident across graph replays -> FETCH ~0, kernel
//    becomes a pure ~134MB write stream. Floor ~22-27us.

typedef float f32x4 __attribute__((ext_vector_type(4)));

constexpr int   T    = 256;
constexpr int   TV   = T / 4;     // 64 float4 per row
constexpr int   CT   = 32;        // timesteps per chunk
constexpr int   CV   = CT / 4;    // 8 float4 per row-chunk
constexpr int   NCH  = T / CT;    // 8 chunks
constexpr int   SEQB = 64;        // sequences per block (= 1 wave)
constexpr int   RP   = CT + 1;    // padded LDS row stride (floats)
constexpr float TAU  = 0.125f;
constexpr float VTH  = 1.0f;

__global__ __launch_bounds__(64)
void lif_fwd(const f32x4* __restrict__ x, f32x4* __restrict__ out, int nseq) {
    __shared__ float lds[2 * SEQB * RP];   // 2 * 8448 B = 16.9 KB
    float* bufA = lds;                     // scan/store buffer
    float* bufB = lds + SEQB * RP;         // prefetch-landing buffer

    const int tid  = threadIdx.x;          // 0..63
    const int srow = tid >> 3;             // 0..7 : seq-subrow in coop phases
    const int k    = tid & 7;              // 0..7 : float4 within row-chunk
    const int bseq = blockIdx.x * SEQB;

    // ---- prologue: chunk 0 -> bufA (coalesced: 8 seqs x 128B per j) ----
    #pragma unroll
    for (int j = 0; j < CV; ++j) {
        f32x4 v = x[(size_t)(bseq + j*8 + srow) * TV + k];
        float* d = &bufA[(j*8 + srow) * RP + k*4];
        d[0]=v.x; d[1]=v.y; d[2]=v.z; d[3]=v.w;
    }
    __syncthreads();

    float u = 0.0f;
    #pragma unroll
    for (int ch = 0; ch < NCH; ++ch) {
        // ---- issue prefetch of chunk ch+1 into registers (in flight over scan) ----
        f32x4 r[CV];
        if (ch + 1 < NCH) {
            #pragma unroll
            for (int j = 0; j < CV; ++j)
                r[j] = x[(size_t)(bseq + j*8 + srow) * TV + (ch+1)*CV + k];
        }

        // ---- sequential scan of own row, in place (spike overwrites input) ----
        #pragma unroll
        for (int t = 0; t < CT; ++t) {
            float xv = bufA[tid * RP + t];
            u = u * TAU + xv;
            bool b = (u >= VTH);
            bufA[tid * RP + t] = b ? 1.0f : 0.0f;
            u = b ? 0.0f : u;
        }
        __syncthreads();   // single-wave barrier: cheap; orders scan vs coop store

        // ---- cooperative coalesced NT store of chunk ch from bufA ----
        // wave-level store = 64 lanes x 16B contiguous = 1KB, full lines ->
        // NT (no cache allocate) is safe; output never re-read.
        #pragma unroll
        for (int j = 0; j < CV; ++j) {
            const float* p = &bufA[(j*8 + srow) * RP + k*4];
            f32x4 v; v.x=p[0]; v.y=p[1]; v.z=p[2]; v.w=p[3];
            __builtin_nontemporal_store(v, &out[(size_t)(bseq + j*8 + srow) * TV + ch*CV + k]);
        }
        // ---- land prefetch regs into bufB ----
        if (ch + 1 < NCH) {
            #pragma unroll
            for (int j = 0; j < CV; ++j) {
                float* d = &bufB[(j*8 + srow) * RP + k*4];
                f32x4 v = r[j];
                d[0]=v.x; d[1]=v.y; d[2]=v.z; d[3]=v.w;
            }
        }
        __syncthreads();

        float* tmp = bufA; bufA = bufB; bufB = tmp;  // unrolled -> compile-time
    }
}

extern "C" void kernel_launch(void* const* d_in, const int* in_sizes, int n_in,
                              void* d_out, int out_size, void* d_ws, size_t ws_size,
                              hipStream_t stream) {
    const float* x = (const float*)d_in[0];
    float* out = (float*)d_out;

    int nseq = in_sizes[0] / T;            // 131072 sequences
    int grid = nseq / SEQB;                // 2048 blocks, exact

    lif_fwd<<<grid, SEQB, 0, stream>>>(
        (const f32x4*)x, (f32x4*)out, nseq);
}